// Round 1
// baseline (146.416 us; speedup 1.0000x reference)
//
#include <hip/hip_runtime.h>
#include <math.h>

// Problem constants (fixed by setup_inputs): N_ref=128, N_src=128, D=256.
#define NREF 128
#define NSRC 128
#define DIM  256
#define EPS  1e-5f

// ---------------------------------------------------------------------------
// K1: feat_score_mat[i][j] = dot(ref_feats[i], src_feats[j]).
// One block per row i; thread j computes column j with float4 dots.
// ---------------------------------------------------------------------------
__global__ __launch_bounds__(128) void feat_kernel(
    const float* __restrict__ ref_feats,
    const float* __restrict__ src_feats,
    float* __restrict__ feat_mat)
{
    __shared__ __align__(16) float refrow[DIM];
    const int i = blockIdx.x;
    const int t = threadIdx.x;
    refrow[t]       = ref_feats[i * DIM + t];
    refrow[t + 128] = ref_feats[i * DIM + 128 + t];
    __syncthreads();

    const float4* __restrict__ src4 = (const float4*)(src_feats + t * DIM);
    const float4* __restrict__ ref4 = (const float4*)refrow;
    float acc = 0.f;
#pragma unroll
    for (int k = 0; k < DIM / 4; ++k) {
        float4 a = ref4[k];
        float4 b = src4[k];
        acc += a.x * b.x + a.y * b.y + a.z * b.z + a.w * b.w;
    }
    feat_mat[i * NSRC + t] = acc;
}

// ---------------------------------------------------------------------------
// K2: everything else, single block of 256 threads.
// ---------------------------------------------------------------------------
__global__ __launch_bounds__(256) void rest_kernel(
    const float* __restrict__ points_c,
    const float* __restrict__ trans,
    const float* __restrict__ feat_mat,
    const float* __restrict__ W1, const float* __restrict__ b1,
    const float* __restrict__ g1, const float* __restrict__ bt1,
    const float* __restrict__ W2, const float* __restrict__ b2,
    const float* __restrict__ g2, const float* __restrict__ bt2,
    const float* __restrict__ W3, const float* __restrict__ b3,
    float* __restrict__ out)
{
    __shared__ float px[256], py[256], pz[256], nsq[256];
    __shared__ float red[4];
    __shared__ float min_dist[256];   // [row maxes of exp(-d) | col maxes]
    __shared__ int   match_idx[256];  // argmax indices for dist
    __shared__ float match_feat[256]; // [row maxes of feat | col maxes]
    __shared__ int   feat_idx[256];   // argmax indices for feat
    __shared__ float feat_score[256];
    __shared__ float match_dist[256];
    __shared__ __align__(16) float geo[512];
    __shared__ float y1[256];
    __shared__ __align__(16) float h1[256];
    __shared__ float y2[128];
    __shared__ float h2[128];

    const int t = threadIdx.x;

    // ---- load points; transform src half (rows 128..255) ----
    float x = points_c[3 * t + 0];
    float y = points_c[3 * t + 1];
    float z = points_c[3 * t + 2];
    if (t >= NREF) {
        float nx = trans[0] * x + trans[1] * y + trans[2]  * z + trans[3];
        float ny = trans[4] * x + trans[5] * y + trans[6]  * z + trans[7];
        float nz = trans[8] * x + trans[9] * y + trans[10] * z + trans[11];
        x = nx; y = ny; z = nz;
    }
    px[t] = x; py[t] = y; pz[t] = z;
    __syncthreads();

    // ---- centroid (mean over 256 points) ----
    if (t < 3) {
        const float* arr = (t == 0) ? px : ((t == 1) ? py : pz);
        float s = 0.f;
        for (int k = 0; k < 256; ++k) s += arr[k];
        red[t] = s * (1.0f / 256.0f);
    }
    __syncthreads();
    x -= red[0]; y -= red[1]; z -= red[2];
    nsq[t] = x * x + y * y + z * z;
    __syncthreads();

    // ---- max norm ----
    if (t == 0) {
        float m = 0.f;
        for (int k = 0; k < 256; ++k) m = fmaxf(m, nsq[k]);
        red[3] = 1.0f / sqrtf(m);
    }
    __syncthreads();
    const float inv_m = red[3];
    x *= inv_m; y *= inv_m; z *= inv_m;
    px[t] = x; py[t] = y; pz[t] = z;
    nsq[t] = x * x + y * y + z * z;
    __syncthreads();

    // ---- dist_mat = exp(-clamp(d,0)) row/col max+argmax (recomputed on the fly).
    // Row scan (thread i) and col scan (thread 128+j) use identical expression
    // ordering so the shared best-pair entry is bitwise equal in both halves
    // (preserves jnp stable-sort tie ordering downstream).
    if (t < NREF) {
        const float xi = px[t], yi = py[t], zi = pz[t], ni = nsq[t];
        float best = -1.f; int bi = 0;
        for (int j = 0; j < NSRC; ++j) {
            float d = ni + nsq[128 + j]
                    - 2.0f * (xi * px[128 + j] + yi * py[128 + j] + zi * pz[128 + j]);
            d = fmaxf(d, 0.f);
            float v = expf(-d);
            if (v > best) { best = v; bi = j; }
        }
        min_dist[t] = best; match_idx[t] = bi;
    } else {
        const int j = t - 128;
        const float xj = px[t], yj = py[t], zj = pz[t], nj = nsq[t];
        float best = -1.f; int bi = 0;
        for (int i = 0; i < NREF; ++i) {
            float d = nsq[i] + nj
                    - 2.0f * (px[i] * xj + py[i] * yj + pz[i] * zj);
            d = fmaxf(d, 0.f);
            float v = expf(-d);
            if (v > best) { best = v; bi = i; }
        }
        min_dist[t] = best; match_idx[t] = bi;
    }

    // ---- feat_score_mat row/col max+argmax (values from ws: exact ties) ----
    if (t < NREF) {
        float best = -2.f; int bi = 0;
        for (int j = 0; j < NSRC; ++j) {
            float v = feat_mat[t * NSRC + j];
            if (v > best) { best = v; bi = j; }
        }
        match_feat[t] = best; feat_idx[t] = bi;
    } else {
        const int j = t - 128;
        float best = -2.f; int bi = 0;
        for (int i = 0; i < NREF; ++i) {
            float v = feat_mat[i * NSRC + j];
            if (v > best) { best = v; bi = i; }
        }
        match_feat[t] = best; feat_idx[t] = bi;
    }
    __syncthreads();

    // ---- gathers ----
    if (t < NREF) {
        feat_score[t] = feat_mat[t * NSRC + match_idx[t]];
        const int j = feat_idx[t];
        float d = nsq[t] + nsq[128 + j]
                - 2.0f * (px[t] * px[128 + j] + py[t] * py[128 + j] + pz[t] * pz[128 + j]);
        d = fmaxf(d, 0.f);
        match_dist[t] = expf(-d);
    } else {
        const int j = t - 128;
        feat_score[t] = feat_mat[match_idx[t] * NSRC + j];
        const int i = feat_idx[t];
        float d = nsq[i] + nsq[t]
                - 2.0f * (px[i] * px[t] + py[i] * py[t] + pz[i] * pz[t]);
        d = fmaxf(d, 0.f);
        match_dist[t] = expf(-d);
    }
    __syncthreads();

    // ---- stable descending ranks (== jnp.argsort(-v), stable) ----
    {
        const float v = min_dist[t];
        int r = 0;
        for (int j = 0; j < 256; ++j) {
            float u = min_dist[j];
            r += (u > v) || (u == v && j < t);
        }
        geo[r] = v * feat_score[t];

        const float w = match_feat[t];
        int r2 = 0;
        for (int j = 0; j < 256; ++j) {
            float u = match_feat[j];
            r2 += (u > w) || (u == w && j < t);
        }
        geo[256 + r2] = match_dist[t] * w;
    }
    __syncthreads();

    // ---- MLP layer 1: y1[c] = geo(512) . W1[c,:] + b1[c] ----
    {
        const float4* __restrict__ gv = (const float4*)geo;
        const float4* __restrict__ wv = (const float4*)(W1 + t * 512);
        float acc = 0.f;
        for (int k = 0; k < 128; ++k) {
            float4 a = gv[k]; float4 b = wv[k];
            acc += a.x * b.x + a.y * b.y + a.z * b.z + a.w * b.w;
        }
        y1[t] = acc + b1[t];
    }
    __syncthreads();
    // GroupNorm(8 groups of 32) + ReLU
    {
        const int g = t >> 5;
        float s = 0.f;
        for (int k = 0; k < 32; ++k) s += y1[g * 32 + k];
        const float mean = s * (1.0f / 32.0f);
        float q = 0.f;
        for (int k = 0; k < 32; ++k) { float d = y1[g * 32 + k] - mean; q += d * d; }
        const float var = q * (1.0f / 32.0f);
        float xn = (y1[t] - mean) * rsqrtf(var + EPS);
        h1[t] = fmaxf(xn * g1[t] + bt1[t], 0.f);
    }
    __syncthreads();

    // ---- MLP layer 2: y2[c] = h1(256) . W2[c,:] + b2[c], c < 128 ----
    if (t < 128) {
        const float4* __restrict__ hv = (const float4*)h1;
        const float4* __restrict__ wv = (const float4*)(W2 + t * 256);
        float acc = 0.f;
        for (int k = 0; k < 64; ++k) {
            float4 a = hv[k]; float4 b = wv[k];
            acc += a.x * b.x + a.y * b.y + a.z * b.z + a.w * b.w;
        }
        y2[t] = acc + b2[t];
    }
    __syncthreads();
    // GroupNorm(8 groups of 16) + ReLU
    if (t < 128) {
        const int g = t >> 4;
        float s = 0.f;
        for (int k = 0; k < 16; ++k) s += y2[g * 16 + k];
        const float mean = s * (1.0f / 16.0f);
        float q = 0.f;
        for (int k = 0; k < 16; ++k) { float d = y2[g * 16 + k] - mean; q += d * d; }
        const float var = q * (1.0f / 16.0f);
        float xn = (y2[t] - mean) * rsqrtf(var + EPS);
        h2[t] = fmaxf(xn * g2[t] + bt2[t], 0.f);
    }
    __syncthreads();

    // ---- output layer: 2 values ----
    if (t < 2) {
        float acc = 0.f;
        for (int k = 0; k < 128; ++k) acc += h2[k] * W3[t * 128 + k];
        out[t] = acc + b3[t];
    }
}

// ---------------------------------------------------------------------------
extern "C" void kernel_launch(void* const* d_in, const int* in_sizes, int n_in,
                              void* d_out, int out_size, void* d_ws, size_t ws_size,
                              hipStream_t stream)
{
    const float* points_c  = (const float*)d_in[0];
    const float* ref_feats = (const float*)d_in[1];
    const float* src_feats = (const float*)d_in[2];
    const float* trans     = (const float*)d_in[3];
    const float* W1  = (const float*)d_in[4];
    const float* b1  = (const float*)d_in[5];
    const float* g1  = (const float*)d_in[6];
    const float* bt1 = (const float*)d_in[7];
    const float* W2  = (const float*)d_in[8];
    const float* b2  = (const float*)d_in[9];
    const float* g2  = (const float*)d_in[10];
    const float* bt2 = (const float*)d_in[11];
    const float* W3  = (const float*)d_in[12];
    const float* b3  = (const float*)d_in[13];
    // d_in[14] = ref_length (int, == 128): fixed at compile time.

    float* feat_mat = (float*)d_ws;  // 128*128 floats = 64 KB

    feat_kernel<<<dim3(NREF), dim3(128), 0, stream>>>(ref_feats, src_feats, feat_mat);
    rest_kernel<<<dim3(1), dim3(256), 0, stream>>>(
        points_c, trans, feat_mat,
        W1, b1, g1, bt1, W2, b2, g2, bt2, W3, b3,
        (float*)d_out);
}

// Round 2
// 130.180 us; speedup vs baseline: 1.1247x; 1.1247x over previous
//
#include <hip/hip_runtime.h>
#include <math.h>

// Problem constants (fixed by setup_inputs): N_ref=128, N_src=128, D=256.
#define NREF 128
#define NSRC 128
#define DIM  256
#define EPS  1e-5f

// ---------------------------------------------------------------------------
// K1: feat_score_mat[i][j] = dot(ref_feats[i], src_feats[j]).
// One block per row i, 256 threads = 4 waves. Each wave handles 32 columns;
// for a column, the 64 lanes stride K with float4 (64*16B = the whole 1 KB
// src row in ONE coalesced instruction), then shuffle-tree reduce.
// ---------------------------------------------------------------------------
__global__ __launch_bounds__(256) void feat_kernel(
    const float* __restrict__ ref_feats,
    const float* __restrict__ src_feats,
    float* __restrict__ feat_mat)
{
    __shared__ __align__(16) float refrow[DIM];
    const int i = blockIdx.x;
    const int t = threadIdx.x;
    if (t < 64) ((float4*)refrow)[t] = ((const float4*)(ref_feats + i * DIM))[t];
    __syncthreads();

    const int w = t >> 6, l = t & 63;
    const float4 r = ((const float4*)refrow)[l];

    for (int m = 0; m < 32; ++m) {
        const int j = w * 32 + m;
        const float4 a = ((const float4*)(src_feats + j * DIM))[l];
        float acc = a.x * r.x + a.y * r.y + a.z * r.z + a.w * r.w;
        acc += __shfl_down(acc, 32);
        acc += __shfl_down(acc, 16);
        acc += __shfl_down(acc, 8);
        acc += __shfl_down(acc, 4);
        acc += __shfl_down(acc, 2);
        acc += __shfl_down(acc, 1);
        if (l == 0) feat_mat[i * NSRC + j] = acc;
    }
}

// ---------------------------------------------------------------------------
// K2: everything else. 1 block x 1024 threads (16 waves) for latency hiding.
// ---------------------------------------------------------------------------
__global__ __launch_bounds__(1024) void rest_kernel(
    const float* __restrict__ points_c,
    const float* __restrict__ trans,
    const float* __restrict__ feat_mat,
    const float* __restrict__ W1, const float* __restrict__ b1,
    const float* __restrict__ g1, const float* __restrict__ bt1,
    const float* __restrict__ W2, const float* __restrict__ b2,
    const float* __restrict__ g2, const float* __restrict__ bt2,
    const float* __restrict__ W3, const float* __restrict__ b3,
    float* __restrict__ out)
{
    __shared__ float px[256], py[256], pz[256], nsq[256];
    __shared__ float wred[16];
    __shared__ float red[4];
    // chunked argmax partials: [q][rc], q=0..3 chunks of the 128-long scan
    __shared__ float pvD[1024]; __shared__ int piD[1024];
    __shared__ float pvF[1024]; __shared__ int piF[1024];
    __shared__ float min_dist[256];   __shared__ int match_idx[256];
    __shared__ float match_feat[256]; __shared__ int feat_idx[256];
    __shared__ float feat_score[256], match_dist[256];
    __shared__ int prD[1024]; __shared__ int prF[1024];   // rank partials
    __shared__ __align__(16) float geo[512];
    __shared__ float y1[256];
    __shared__ __align__(16) float h1[256];
    __shared__ float y2[128], h2[128];

    const int t    = threadIdx.x;
    const int wave = t >> 6;
    const int lane = t & 63;

    // ---- P0: load points, transform src half (registers only) ----
    float x = 0.f, y = 0.f, z = 0.f;
    if (t < 256) {
        x = points_c[3 * t + 0];
        y = points_c[3 * t + 1];
        z = points_c[3 * t + 2];
        if (t >= NREF) {
            float nx = trans[0] * x + trans[1] * y + trans[2]  * z + trans[3];
            float ny = trans[4] * x + trans[5] * y + trans[6]  * z + trans[7];
            float nz = trans[8] * x + trans[9] * y + trans[10] * z + trans[11];
            x = nx; y = ny; z = nz;
        }
        // centroid partial sums (waves 0..3 exactly cover t<256)
        float sx = x, sy = y, sz = z;
        for (int off = 32; off >= 1; off >>= 1) {
            sx += __shfl_down(sx, off);
            sy += __shfl_down(sy, off);
            sz += __shfl_down(sz, off);
        }
        if (lane == 0) {
            wred[wave]     = sx;
            wred[4 + wave] = sy;
            wred[8 + wave] = sz;
        }
    }
    __syncthreads();
    if (t == 0) {
        red[0] = (wred[0] + wred[1] + wred[2] + wred[3]) * (1.0f / 256.0f);
        red[1] = (wred[4] + wred[5] + wred[6] + wred[7]) * (1.0f / 256.0f);
        red[2] = (wred[8] + wred[9] + wred[10] + wred[11]) * (1.0f / 256.0f);
    }
    __syncthreads();

    // ---- P1: center, max-norm reduce, normalize ----
    if (t < 256) {
        x -= red[0]; y -= red[1]; z -= red[2];
        float n = x * x + y * y + z * z;
        float mx = n;
        for (int off = 32; off >= 1; off >>= 1)
            mx = fmaxf(mx, __shfl_down(mx, off));
        if (lane == 0) wred[wave] = mx;
    }
    __syncthreads();
    if (t == 0)
        red[3] = 1.0f / sqrtf(fmaxf(fmaxf(wred[0], wred[1]), fmaxf(wred[2], wred[3])));
    __syncthreads();
    if (t < 256) {
        const float inv = red[3];
        x *= inv; y *= inv; z *= inv;
        px[t] = x; py[t] = y; pz[t] = z;
        nsq[t] = x * x + y * y + z * z;
    }
    __syncthreads();

    // ---- P2: chunked row/col argmax scans for dist (recomputed) and feat ----
    // rc<128: row rc of the 128x128 matrices; rc>=128: column rc-128.
    // d(i,j) uses ONE shared expression -> bitwise-identical between row and
    // col scans (preserves jnp stable-sort / argmax tie semantics downstream).
    {
        const int rc = t & 255, q = t >> 8;
        float bdv = -1.f; int bdi = 0;
        float bfv = -2.f; int bfi = 0;
        if (rc < 128) {
            const int i = rc;
            for (int m = 0; m < 32; ++m) {
                const int j = q * 32 + m;
                float d = nsq[i] + nsq[128 + j]
                        - 2.0f * (px[i] * px[128 + j] + py[i] * py[128 + j] + pz[i] * pz[128 + j]);
                d = fmaxf(d, 0.f);
                const float v = expf(-d);
                if (v > bdv) { bdv = v; bdi = j; }
                const float f = feat_mat[i * NSRC + j];
                if (f > bfv) { bfv = f; bfi = j; }
            }
        } else {
            const int j = rc - 128;
            for (int m = 0; m < 32; ++m) {
                const int i = q * 32 + m;
                float d = nsq[i] + nsq[128 + j]
                        - 2.0f * (px[i] * px[128 + j] + py[i] * py[128 + j] + pz[i] * pz[128 + j]);
                d = fmaxf(d, 0.f);
                const float v = expf(-d);
                if (v > bdv) { bdv = v; bdi = i; }
                const float f = feat_mat[i * NSRC + j];
                if (f > bfv) { bfv = f; bfi = i; }
            }
        }
        pvD[q * 256 + rc] = bdv; piD[q * 256 + rc] = bdi;
        pvF[q * 256 + rc] = bfv; piF[q * 256 + rc] = bfi;
    }
    __syncthreads();

    // ---- P3: combine chunks (ascending q + strict > == first occurrence) ----
    if (t < 256) {
        float bv = -1.f; int bi = 0;
        for (int q = 0; q < 4; ++q) {
            const float v = pvD[q * 256 + t];
            if (v > bv) { bv = v; bi = piD[q * 256 + t]; }
        }
        min_dist[t] = bv; match_idx[t] = bi;
        float fv = -2.f; int fi = 0;
        for (int q = 0; q < 4; ++q) {
            const float v = pvF[q * 256 + t];
            if (v > fv) { fv = v; fi = piF[q * 256 + t]; }
        }
        match_feat[t] = fv; feat_idx[t] = fi;
    }
    __syncthreads();

    // ---- P4: gathers ----
    if (t < 256) {
        if (t < NREF) {
            const int i = t;
            feat_score[t] = feat_mat[i * NSRC + match_idx[t]];
            const int j = feat_idx[t];
            float d = nsq[i] + nsq[128 + j]
                    - 2.0f * (px[i] * px[128 + j] + py[i] * py[128 + j] + pz[i] * pz[128 + j]);
            d = fmaxf(d, 0.f);
            match_dist[t] = expf(-d);
        } else {
            const int j = t - 128;
            feat_score[t] = feat_mat[match_idx[t] * NSRC + j];
            const int i = feat_idx[t];
            float d = nsq[i] + nsq[128 + j]
                    - 2.0f * (px[i] * px[128 + j] + py[i] * py[128 + j] + pz[i] * pz[128 + j]);
            d = fmaxf(d, 0.f);
            match_dist[t] = expf(-d);
        }
    }
    __syncthreads();

    // ---- P5: stable descending ranks (== jnp.argsort(-v)), chunked 4x64 ----
    {
        const int e = t & 255, q = t >> 8;
        const float v  = min_dist[e];
        const float wv = match_feat[e];
        int r1 = 0, r2 = 0;
        for (int m = 0; m < 64; ++m) {
            const int j = q * 64 + m;
            const float u  = min_dist[j];
            r1 += (u > v) || (u == v && j < e);
            const float uf = match_feat[j];
            r2 += (uf > wv) || (uf == wv && j < e);
        }
        prD[q * 256 + e] = r1;
        prF[q * 256 + e] = r2;
    }
    __syncthreads();
    if (t < 256) {
        const int r  = prD[t] + prD[256 + t] + prD[512 + t] + prD[768 + t];
        geo[r] = min_dist[t] * feat_score[t];
        const int rf = prF[t] + prF[256 + t] + prF[512 + t] + prF[768 + t];
        geo[256 + rf] = match_dist[t] * match_feat[t];
    }
    __syncthreads();

    // ---- P6: MLP1. Wave w -> outputs 16w..16w+15; lanes stride K (float4,
    // 1 KB coalesced per instruction), shuffle-tree reduce. ----
    {
        const float4* __restrict__ geo4 = (const float4*)geo;
        const float4 ga = geo4[lane];
        const float4 gb = geo4[64 + lane];
        for (int cc = 0; cc < 16; ++cc) {
            const int c = (wave << 4) + cc;
            const float4* __restrict__ wrow = (const float4*)(W1 + c * 512);
            const float4 a = wrow[lane];
            const float4 b = wrow[64 + lane];
            float acc = a.x * ga.x + a.y * ga.y + a.z * ga.z + a.w * ga.w
                      + b.x * gb.x + b.y * gb.y + b.z * gb.z + b.w * gb.w;
            acc += __shfl_down(acc, 32);
            acc += __shfl_down(acc, 16);
            acc += __shfl_down(acc, 8);
            acc += __shfl_down(acc, 4);
            acc += __shfl_down(acc, 2);
            acc += __shfl_down(acc, 1);
            if (lane == 0) y1[c] = acc + b1[c];
        }
    }
    __syncthreads();
    // GroupNorm(8 groups of 32) + ReLU
    if (t < 256) {
        const int g = t >> 5;
        float s = 0.f;
        for (int k = 0; k < 32; ++k) s += y1[(g << 5) + k];
        const float mean = s * (1.0f / 32.0f);
        float q = 0.f;
        for (int k = 0; k < 32; ++k) { const float d = y1[(g << 5) + k] - mean; q += d * d; }
        const float var = q * (1.0f / 32.0f);
        const float xn = (y1[t] - mean) * rsqrtf(var + EPS);
        h1[t] = fmaxf(xn * g1[t] + bt1[t], 0.f);
    }
    __syncthreads();

    // ---- P7: MLP2. Wave w -> outputs 8w..8w+7; one float4/lane covers the
    // whole 256-float row. ----
    {
        const float4* __restrict__ h1v = (const float4*)h1;
        const float4 ha = h1v[lane];
        for (int cc = 0; cc < 8; ++cc) {
            const int c = (wave << 3) + cc;
            const float4 a = ((const float4*)(W2 + c * 256))[lane];
            float acc = a.x * ha.x + a.y * ha.y + a.z * ha.z + a.w * ha.w;
            acc += __shfl_down(acc, 32);
            acc += __shfl_down(acc, 16);
            acc += __shfl_down(acc, 8);
            acc += __shfl_down(acc, 4);
            acc += __shfl_down(acc, 2);
            acc += __shfl_down(acc, 1);
            if (lane == 0) y2[c] = acc + b2[c];
        }
    }
    __syncthreads();
    // GroupNorm(8 groups of 16) + ReLU
    if (t < 128) {
        const int g = t >> 4;
        float s = 0.f;
        for (int k = 0; k < 16; ++k) s += y2[(g << 4) + k];
        const float mean = s * (1.0f / 16.0f);
        float q = 0.f;
        for (int k = 0; k < 16; ++k) { const float d = y2[(g << 4) + k] - mean; q += d * d; }
        const float var = q * (1.0f / 16.0f);
        const float xn = (y2[t] - mean) * rsqrtf(var + EPS);
        h2[t] = fmaxf(xn * g2[t] + bt2[t], 0.f);
    }
    __syncthreads();

    // ---- P8: output layer (2 values), one wave each ----
    if (wave < 2) {
        float acc = W3[wave * 128 + lane] * h2[lane]
                  + W3[wave * 128 + 64 + lane] * h2[64 + lane];
        acc += __shfl_down(acc, 32);
        acc += __shfl_down(acc, 16);
        acc += __shfl_down(acc, 8);
        acc += __shfl_down(acc, 4);
        acc += __shfl_down(acc, 2);
        acc += __shfl_down(acc, 1);
        if (lane == 0) out[wave] = acc + b3[wave];
    }
}

// ---------------------------------------------------------------------------
extern "C" void kernel_launch(void* const* d_in, const int* in_sizes, int n_in,
                              void* d_out, int out_size, void* d_ws, size_t ws_size,
                              hipStream_t stream)
{
    const float* points_c  = (const float*)d_in[0];
    const float* ref_feats = (const float*)d_in[1];
    const float* src_feats = (const float*)d_in[2];
    const float* trans     = (const float*)d_in[3];
    const float* W1  = (const float*)d_in[4];
    const float* b1  = (const float*)d_in[5];
    const float* g1  = (const float*)d_in[6];
    const float* bt1 = (const float*)d_in[7];
    const float* W2  = (const float*)d_in[8];
    const float* b2  = (const float*)d_in[9];
    const float* g2  = (const float*)d_in[10];
    const float* bt2 = (const float*)d_in[11];
    const float* W3  = (const float*)d_in[12];
    const float* b3  = (const float*)d_in[13];
    // d_in[14] = ref_length (int, == 128): fixed at compile time.

    float* feat_mat = (float*)d_ws;  // 128*128 floats = 64 KB

    feat_kernel<<<dim3(NREF), dim3(256), 0, stream>>>(ref_feats, src_feats, feat_mat);
    rest_kernel<<<dim3(1), dim3(1024), 0, stream>>>(
        points_c, trans, feat_mat,
        W1, b1, g1, bt1, W2, b2, g2, bt2, W3, b3,
        (float*)d_out);
}

// Round 3
// 104.489 us; speedup vs baseline: 1.4013x; 1.2459x over previous
//
#include <hip/hip_runtime.h>
#include <math.h>

// Problem constants (fixed by setup_inputs): N_ref=128, N_src=128, D=256.
#define NREF 128
#define NSRC 128
#define DIM  256
#define EPS  1e-5f

// ---------------------------------------------------------------------------
// K1: feat_score_mat[i][j] = dot(ref_feats[i], src_feats[j]).
// One block per row i, 512 threads = 8 waves; each wave 16 columns with
// 2-column ILP (two shuffle-reduce chains in flight).
// ---------------------------------------------------------------------------
__global__ __launch_bounds__(512) void feat_kernel(
    const float* __restrict__ ref_feats,
    const float* __restrict__ src_feats,
    float* __restrict__ feat_mat)
{
    __shared__ __align__(16) float refrow[DIM];
    const int i = blockIdx.x;
    const int t = threadIdx.x;
    if (t < 64) ((float4*)refrow)[t] = ((const float4*)(ref_feats + i * DIM))[t];
    __syncthreads();

    const int w = t >> 6, l = t & 63;
    const float4 r = ((const float4*)refrow)[l];

    for (int m = 0; m < 16; m += 2) {
        const int j0 = w * 16 + m;
        const int j1 = j0 + 1;
        const float4 a0 = ((const float4*)(src_feats + j0 * DIM))[l];
        const float4 a1 = ((const float4*)(src_feats + j1 * DIM))[l];
        float acc0 = a0.x * r.x + a0.y * r.y + a0.z * r.z + a0.w * r.w;
        float acc1 = a1.x * r.x + a1.y * r.y + a1.z * r.z + a1.w * r.w;
        for (int off = 32; off >= 1; off >>= 1) {
            acc0 += __shfl_down(acc0, off);
            acc1 += __shfl_down(acc1, off);
        }
        if (l == 0) {
            feat_mat[i * NSRC + j0] = acc0;
            feat_mat[i * NSRC + j1] = acc1;
        }
    }
}

// ---------------------------------------------------------------------------
// K2: points + dist/feat argmax + gathers + stable ranks -> geo[512] (global).
// 1 block x 1024 threads. geo ALIASES feat_mat[0..511]: written only after
// the last feat_mat read (barrier-ordered within this single block).
// ---------------------------------------------------------------------------
__global__ __launch_bounds__(1024) void geo_kernel(
    const float* __restrict__ points_c,
    const float* __restrict__ trans,
    const float* __restrict__ feat_mat,
    float* __restrict__ geo_out)
{
    __shared__ float px[256], py[256], pz[256], nsq[256];
    __shared__ float wred[16];
    __shared__ float red[4];
    __shared__ float pvD[1024]; __shared__ int piD[1024];
    __shared__ float pvF[1024]; __shared__ int piF[1024];
    __shared__ float min_dist[256];   __shared__ int match_idx[256];
    __shared__ float match_feat[256]; __shared__ int feat_idx[256];
    __shared__ float feat_score[256], match_dist[256];
    __shared__ int prD[1024]; __shared__ int prF[1024];

    const int t    = threadIdx.x;
    const int wave = t >> 6;
    const int lane = t & 63;

    // ---- P0: load points, transform src half ----
    float x = 0.f, y = 0.f, z = 0.f;
    if (t < 256) {
        x = points_c[3 * t + 0];
        y = points_c[3 * t + 1];
        z = points_c[3 * t + 2];
        if (t >= NREF) {
            float nx = trans[0] * x + trans[1] * y + trans[2]  * z + trans[3];
            float ny = trans[4] * x + trans[5] * y + trans[6]  * z + trans[7];
            float nz = trans[8] * x + trans[9] * y + trans[10] * z + trans[11];
            x = nx; y = ny; z = nz;
        }
        float sx = x, sy = y, sz = z;
        for (int off = 32; off >= 1; off >>= 1) {
            sx += __shfl_down(sx, off);
            sy += __shfl_down(sy, off);
            sz += __shfl_down(sz, off);
        }
        if (lane == 0) {
            wred[wave]     = sx;
            wred[4 + wave] = sy;
            wred[8 + wave] = sz;
        }
    }
    __syncthreads();
    if (t == 0) {
        red[0] = (wred[0] + wred[1] + wred[2] + wred[3]) * (1.0f / 256.0f);
        red[1] = (wred[4] + wred[5] + wred[6] + wred[7]) * (1.0f / 256.0f);
        red[2] = (wred[8] + wred[9] + wred[10] + wred[11]) * (1.0f / 256.0f);
    }
    __syncthreads();

    // ---- P1: center, max-norm, normalize ----
    if (t < 256) {
        x -= red[0]; y -= red[1]; z -= red[2];
        float n = x * x + y * y + z * z;
        float mx = n;
        for (int off = 32; off >= 1; off >>= 1)
            mx = fmaxf(mx, __shfl_down(mx, off));
        if (lane == 0) wred[wave] = mx;
    }
    __syncthreads();
    if (t == 0)
        red[3] = 1.0f / sqrtf(fmaxf(fmaxf(wred[0], wred[1]), fmaxf(wred[2], wred[3])));
    __syncthreads();
    if (t < 256) {
        const float inv = red[3];
        x *= inv; y *= inv; z *= inv;
        px[t] = x; py[t] = y; pz[t] = z;
        nsq[t] = x * x + y * y + z * z;
    }
    __syncthreads();

    // ---- P2: chunked row/col argmax scans (dist recomputed; feat from ws).
    // d(i,j) uses ONE shared expression -> bitwise-identical row vs col.
    {
        const int rc = t & 255, q = t >> 8;
        float bdv = -1.f; int bdi = 0;
        float bfv = -2.f; int bfi = 0;
        if (rc < 128) {
            const int i = rc;
            for (int m = 0; m < 32; ++m) {
                const int j = q * 32 + m;
                float d = nsq[i] + nsq[128 + j]
                        - 2.0f * (px[i] * px[128 + j] + py[i] * py[128 + j] + pz[i] * pz[128 + j]);
                d = fmaxf(d, 0.f);
                const float v = expf(-d);
                if (v > bdv) { bdv = v; bdi = j; }
                const float f = feat_mat[i * NSRC + j];
                if (f > bfv) { bfv = f; bfi = j; }
            }
        } else {
            const int j = rc - 128;
            for (int m = 0; m < 32; ++m) {
                const int i = q * 32 + m;
                float d = nsq[i] + nsq[128 + j]
                        - 2.0f * (px[i] * px[128 + j] + py[i] * py[128 + j] + pz[i] * pz[128 + j]);
                d = fmaxf(d, 0.f);
                const float v = expf(-d);
                if (v > bdv) { bdv = v; bdi = i; }
                const float f = feat_mat[i * NSRC + j];
                if (f > bfv) { bfv = f; bfi = i; }
            }
        }
        pvD[q * 256 + rc] = bdv; piD[q * 256 + rc] = bdi;
        pvF[q * 256 + rc] = bfv; piF[q * 256 + rc] = bfi;
    }
    __syncthreads();

    // ---- P3: combine chunks (ascending q + strict > == first occurrence) ----
    if (t < 256) {
        float bv = -1.f; int bi = 0;
        for (int q = 0; q < 4; ++q) {
            const float v = pvD[q * 256 + t];
            if (v > bv) { bv = v; bi = piD[q * 256 + t]; }
        }
        min_dist[t] = bv; match_idx[t] = bi;
        float fv = -2.f; int fi = 0;
        for (int q = 0; q < 4; ++q) {
            const float v = pvF[q * 256 + t];
            if (v > fv) { fv = v; fi = piF[q * 256 + t]; }
        }
        match_feat[t] = fv; feat_idx[t] = fi;
    }
    __syncthreads();

    // ---- P4: gathers (last feat_mat reads) ----
    if (t < 256) {
        if (t < NREF) {
            const int i = t;
            feat_score[t] = feat_mat[i * NSRC + match_idx[t]];
            const int j = feat_idx[t];
            float d = nsq[i] + nsq[128 + j]
                    - 2.0f * (px[i] * px[128 + j] + py[i] * py[128 + j] + pz[i] * pz[128 + j]);
            d = fmaxf(d, 0.f);
            match_dist[t] = expf(-d);
        } else {
            const int j = t - 128;
            feat_score[t] = feat_mat[match_idx[t] * NSRC + j];
            const int i = feat_idx[t];
            float d = nsq[i] + nsq[128 + j]
                    - 2.0f * (px[i] * px[128 + j] + py[i] * py[128 + j] + pz[i] * pz[128 + j]);
            d = fmaxf(d, 0.f);
            match_dist[t] = expf(-d);
        }
    }
    __syncthreads();   // all feat_mat reads drained; geo_out may alias it now

    // ---- P5: stable descending ranks (== jnp.argsort(-v)), chunked 4x64 ----
    {
        const int e = t & 255, q = t >> 8;
        const float v  = min_dist[e];
        const float wv = match_feat[e];
        int r1 = 0, r2 = 0;
        for (int m = 0; m < 64; ++m) {
            const int j = q * 64 + m;
            const float u  = min_dist[j];
            r1 += (u > v) || (u == v && j < e);
            const float uf = match_feat[j];
            r2 += (uf > wv) || (uf == wv && j < e);
        }
        prD[q * 256 + e] = r1;
        prF[q * 256 + e] = r2;
    }
    __syncthreads();
    if (t < 256) {
        const int r  = prD[t] + prD[256 + t] + prD[512 + t] + prD[768 + t];
        geo_out[r] = min_dist[t] * feat_score[t];
        const int rf = prF[t] + prF[256 + t] + prF[512 + t] + prF[768 + t];
        geo_out[256 + rf] = match_dist[t] * match_feat[t];
    }
}

// ---------------------------------------------------------------------------
// K3: y1[c] = geo . W1[c,:] + b1[c]. 256 blocks x 64 threads (one CU each):
// W1's 512 KB streamed chip-wide in parallel.
// ---------------------------------------------------------------------------
__global__ __launch_bounds__(64) void mlp1_kernel(
    const float* __restrict__ geo,
    const float* __restrict__ W1, const float* __restrict__ b1,
    float* __restrict__ y1)
{
    const int c = blockIdx.x, l = threadIdx.x;
    const float4 ga = ((const float4*)geo)[l];
    const float4 gb = ((const float4*)geo)[64 + l];
    const float4* __restrict__ wrow = (const float4*)(W1 + c * 512);
    const float4 a = wrow[l];
    const float4 b = wrow[64 + l];
    float acc = a.x * ga.x + a.y * ga.y + a.z * ga.z + a.w * ga.w
              + b.x * gb.x + b.y * gb.y + b.z * gb.z + b.w * gb.w;
    acc += __shfl_down(acc, 32);
    acc += __shfl_down(acc, 16);
    acc += __shfl_down(acc, 8);
    acc += __shfl_down(acc, 4);
    acc += __shfl_down(acc, 2);
    acc += __shfl_down(acc, 1);
    if (l == 0) y1[c] = acc + b1[c];
}

// ---------------------------------------------------------------------------
// K4: h1 = relu(GN8(y1)*g1+bt1); y2[c] = h1 . W2[c,:] + b2[c].
// 128 blocks x 64 threads; GN1 recomputed per block (tiny, L3-warm).
// Lane l's W2 float4 covers exactly channels 4l..4l+3 == its own h values.
// ---------------------------------------------------------------------------
__global__ __launch_bounds__(64) void mlp2_kernel(
    const float* __restrict__ y1,
    const float* __restrict__ g1, const float* __restrict__ bt1,
    const float* __restrict__ W2, const float* __restrict__ b2,
    float* __restrict__ y2)
{
    __shared__ __align__(16) float y1s[256];
    __shared__ float stats[16];   // mean[8], invstd[8]
    const int c = blockIdx.x, l = threadIdx.x;
    ((float4*)y1s)[l] = ((const float4*)y1)[l];
    __syncthreads();
    if (l < 8) {
        float s = 0.f;
        for (int k = 0; k < 32; ++k) s += y1s[(l << 5) + k];
        const float mean = s * (1.0f / 32.0f);
        float q = 0.f;
        for (int k = 0; k < 32; ++k) { const float d = y1s[(l << 5) + k] - mean; q += d * d; }
        const float var = q * (1.0f / 32.0f);
        stats[l] = mean;
        stats[8 + l] = rsqrtf(var + EPS);
    }
    __syncthreads();
    const float4 gg = ((const float4*)g1)[l];
    const float4 bb = ((const float4*)bt1)[l];
    const int g = l >> 3;
    const float mean = stats[g], inv = stats[8 + g];
    const float4 yv = ((const float4*)y1s)[l];
    float4 h;
    h.x = fmaxf((yv.x - mean) * inv * gg.x + bb.x, 0.f);
    h.y = fmaxf((yv.y - mean) * inv * gg.y + bb.y, 0.f);
    h.z = fmaxf((yv.z - mean) * inv * gg.z + bb.z, 0.f);
    h.w = fmaxf((yv.w - mean) * inv * gg.w + bb.w, 0.f);
    const float4 wv = ((const float4*)(W2 + c * 256))[l];
    float acc = wv.x * h.x + wv.y * h.y + wv.z * h.z + wv.w * h.w;
    acc += __shfl_down(acc, 32);
    acc += __shfl_down(acc, 16);
    acc += __shfl_down(acc, 8);
    acc += __shfl_down(acc, 4);
    acc += __shfl_down(acc, 2);
    acc += __shfl_down(acc, 1);
    if (l == 0) y2[c] = acc + b2[c];
}

// ---------------------------------------------------------------------------
// K5: h2 = relu(GN8(y2)*g2+bt2); out = h2 @ W3.T + b3. 1 block x 128.
// ---------------------------------------------------------------------------
__global__ __launch_bounds__(128) void final_kernel(
    const float* __restrict__ y2,
    const float* __restrict__ g2, const float* __restrict__ bt2,
    const float* __restrict__ W3, const float* __restrict__ b3,
    float* __restrict__ out)
{
    __shared__ float y2s[128], h2[128];
    const int t = threadIdx.x;
    y2s[t] = y2[t];
    __syncthreads();
    {
        const int g = t >> 4;
        float s = 0.f;
        for (int k = 0; k < 16; ++k) s += y2s[(g << 4) + k];
        const float mean = s * (1.0f / 16.0f);
        float q = 0.f;
        for (int k = 0; k < 16; ++k) { const float d = y2s[(g << 4) + k] - mean; q += d * d; }
        const float var = q * (1.0f / 16.0f);
        const float xn = (y2s[t] - mean) * rsqrtf(var + EPS);
        h2[t] = fmaxf(xn * g2[t] + bt2[t], 0.f);
    }
    __syncthreads();
    const int wave = t >> 6, lane = t & 63;
    float acc = W3[wave * 128 + lane] * h2[lane]
              + W3[wave * 128 + 64 + lane] * h2[64 + lane];
    acc += __shfl_down(acc, 32);
    acc += __shfl_down(acc, 16);
    acc += __shfl_down(acc, 8);
    acc += __shfl_down(acc, 4);
    acc += __shfl_down(acc, 2);
    acc += __shfl_down(acc, 1);
    if (lane == 0) out[wave] = acc + b3[wave];
}

// ---------------------------------------------------------------------------
extern "C" void kernel_launch(void* const* d_in, const int* in_sizes, int n_in,
                              void* d_out, int out_size, void* d_ws, size_t ws_size,
                              hipStream_t stream)
{
    const float* points_c  = (const float*)d_in[0];
    const float* ref_feats = (const float*)d_in[1];
    const float* src_feats = (const float*)d_in[2];
    const float* trans     = (const float*)d_in[3];
    const float* W1  = (const float*)d_in[4];
    const float* b1  = (const float*)d_in[5];
    const float* g1  = (const float*)d_in[6];
    const float* bt1 = (const float*)d_in[7];
    const float* W2  = (const float*)d_in[8];
    const float* b2  = (const float*)d_in[9];
    const float* g2  = (const float*)d_in[10];
    const float* bt2 = (const float*)d_in[11];
    const float* W3  = (const float*)d_in[12];
    const float* b3  = (const float*)d_in[13];
    // d_in[14] = ref_length (int, == 128): fixed at compile time.

    // ws layout (total 64 KB): feat_mat occupies floats [0, 16384).
    // After geo_kernel's last feat_mat read, [0,512) is reused for geo,
    // [512,768) for y1, [768,896) for y2 (stream-ordered, barrier-safe).
    float* feat_mat = (float*)d_ws;
    float* geo = feat_mat;
    float* y1  = feat_mat + 512;
    float* y2  = feat_mat + 768;

    feat_kernel<<<dim3(NREF), dim3(512), 0, stream>>>(ref_feats, src_feats, feat_mat);
    geo_kernel<<<dim3(1), dim3(1024), 0, stream>>>(points_c, trans, feat_mat, geo);
    mlp1_kernel<<<dim3(256), dim3(64), 0, stream>>>(geo, W1, b1, y1);
    mlp2_kernel<<<dim3(128), dim3(64), 0, stream>>>(y1, g1, bt1, W2, b2, y2);
    final_kernel<<<dim3(1), dim3(128), 0, stream>>>(y2, g2, bt2, W3, b3, (float*)d_out);
}